// Round 6
// baseline (268.621 us; speedup 1.0000x reference)
//
#include <hip/hip_runtime.h>
#include <cstdint>

#define BATCH 4
#define CPD 64
#define RES 64
#define NS 131072
#define NF 512
#define FS 2048
#define HID 16

typedef _Float16 __attribute__((ext_vector_type(8))) f16x8;
typedef float __attribute__((ext_vector_type(16))) f32x16;

// ---------------------------------------------------------------------------
// K1: damping + sequential scan (unchanged; tiny cost, passed)
// ---------------------------------------------------------------------------
__global__ __launch_bounds__(256) void k_scan(const float* __restrict__ forces,
                                              const float* __restrict__ dmod,
                                              const float* __restrict__ dparam,
                                              float* __restrict__ damped_t) {
  __shared__ float f_lds[64][129];
  __shared__ float d_lds[64][129];
  const int b = blockIdx.x;
  const int tid = threadIdx.x;
  float dbase = 0.f, carry = 0.f;
  if (tid < 64) {
    float dp = dparam[tid];
    dbase = 0.5f + (0.9999f - 0.5f) / (1.f + expf(-dp));
  }
  for (int ch = 0; ch < 4; ++ch) {
    const int t0 = ch * 128;
    __syncthreads();
    for (int idx = tid; idx < 64 * 128; idx += 256) {
      int c = idx >> 7, tl = idx & 127;
      f_lds[c][tl] = forces[(b * CPD + c) * NF + t0 + tl];
      d_lds[c][tl] = dmod[(b * CPD + c) * NF + t0 + tl];
    }
    __syncthreads();
    if (tid < 64) {
      const int c = tid;
      for (int tl = 0; tl < 128; ++tl) {
        float d = dbase - fabsf(d_lds[c][tl]);
        d = fminf(fmaxf(d, 0.f), 1.f);
        float f = f_lds[c][tl];
        float out = (ch == 0 && tl == 0) ? f : (f + carry) * d;
        carry = out;
        damped_t[(b * NF + t0 + tl) * CPD + c] = out;
      }
    }
  }
}

// ---------------------------------------------------------------------------
// K2: hypernetwork + routing einsum + to_ctrl (unchanged)
// ---------------------------------------------------------------------------
__global__ __launch_bounds__(256) void k_hyper(const float* __restrict__ damped_t,
                                               const float* __restrict__ routing,
                                               const float* __restrict__ W1,
                                               const float* __restrict__ b1,
                                               const float* __restrict__ W2,
                                               const float* __restrict__ b2,
                                               const float* __restrict__ to_control,
                                               float* __restrict__ routed,
                                               float* __restrict__ to_ctrl) {
  __shared__ float xs[4][64];
  __shared__ float hs[4][16];
  __shared__ float rs[4][64];
  const int blk = blockIdx.x;
  const int b = blk >> 7;
  const int t0 = (blk & 127) * 4;
  const int lt = threadIdx.x >> 6;
  const int d = threadIdx.x & 63;
  const int t = t0 + lt;

  xs[lt][d] = damped_t[(b * NF + t) * CPD + d];
  __syncthreads();
  if (d < HID) {
    float a = b1[d];
    for (int c = 0; c < CPD; ++c) a = fmaf(xs[lt][c], W1[c * HID + d], a);
    hs[lt][d] = a > 0.f ? a : 0.2f * a;
  }
  __syncthreads();
  float hreg[HID];
#pragma unroll
  for (int j = 0; j < HID; ++j) hreg[j] = hs[lt][j];

  float acc = 0.f;
  for (int c = 0; c < CPD; ++c) {
    float w = routing[c * RES + d] + b2[c * RES + d];
    const float* w2p = W2 + c * RES + d;
#pragma unroll
    for (int j = 0; j < HID; ++j) w = fmaf(hreg[j], w2p[j * (CPD * RES)], w);
    acc = fmaf(xs[lt][c], w, acc);
  }
  routed[(b * RES + d) * NF + t] = acc;
  rs[lt][d] = acc;
  __syncthreads();
  float tc = 0.f;
  for (int q = 0; q < RES; ++q) tc = fmaf(rs[lt][q], to_control[q * CPD + d], tc);
  to_ctrl[(b * CPD + d) * NF + t] = tc;
}

// ---------------------------------------------------------------------------
// K-zero: zero the atomic boundary strips (re-run every launch -> replay safe)
// Strips per channel: [0,32), [32768s-992, 32768s+32) s=1..3, [130080,131072)
// ---------------------------------------------------------------------------
__global__ __launch_bounds__(256) void k_zero(float* __restrict__ reso) {
  const int chan = blockIdx.x;
  const size_t base = (size_t)chan * NS;
  for (int i = threadIdx.x; i < 4096; i += 256) {
    int y;
    if (i < 32) y = i;
    else if (i < 32 + 3072) {
      int s = 1 + ((i - 32) >> 10);
      y = 32768 * s - 992 + ((i - 32) & 1023);
    } else {
      y = 130080 + (i - 3104);
    }
    reso[base + y] = 0.f;
  }
}

// ---------------------------------------------------------------------------
// K3: block-Hankel GEMM conv, 2-phase A-sharing (skewed filter), r6 fix.
//
// C(tau,j)[m][n] += sum_i A_tau[m][i] * B_j[i][n]
//   A_tau[m][i] = e[Q_tau - 32m - 16*sg - i]      (shared by j=0,1)
//   B_j[i][n]   = f[n - 32 + 16*sg + 1024j + i]
//   partial out[Q_tau - 32 + 1024j + n - 32m],  Q_tau = SegB+4096w+1024tau+32
// Phase 0: sg in [0,66) -> taps [n-32, n+1024); Phase 1: sg in [2,66) ->
// taps [n+1024, n+2048). Pair acc(u,0)+acc(u-1,1) = full taps.
// Edge partials via LDS exchange (intra-block) and atomicAdd into zeroed
// strips (inter-block). r6 FIX: the global-top strip [NS-992, NS) has no
// next-seg phase-0 partner -> seg==3, w==7 computes the tau=4 phase-0
// partial (66 supersteps) and folds it into a13 before the atomic.
// Per superstep: 4 A b128 reads + 2 B reads feed 8 MFMAs.
// ---------------------------------------------------------------------------
#define ER_GRAN 4360        // 16B granules allocated (incl. swizzle slack)
#define ER_N 34816          // staged samples: x = 0..34815, er[x]=e[E0-x]*1024
#define FQ 1068             // dwords per filter parity copy

__global__ __launch_bounds__(512, 2) void k_conv(const float* __restrict__ routed,
                                                 const float* __restrict__ noise,
                                                 const float* __restrict__ filters,
                                                 float* __restrict__ outp) {
  __shared__ __align__(16) unsigned char smem[ER_GRAN * 16 + 2 * FQ * 4];
  unsigned short* er = (unsigned short*)smem;
  unsigned* fcp = (unsigned*)(smem + ER_GRAN * 16);

  const int tid = threadIdx.x;
  const int seg = blockIdx.x & 3;
  const int r = (blockIdx.x >> 2) & 63;
  const int b = blockIdx.x >> 8;
  const int SegB = seg * 32768;
  const int E0 = SegB + 32800;        // er[x] = e[E0-x]*1024
  const int chan = b * RES + r;
  const float* rp = routed + chan * NF;
  const float* npz = noise + (size_t)chan * NS;

  // ---- filter staging: parity copies, copy p dword q = taps (2q+p-48, +1) ----
  for (int idx = tid; idx < 2 * FQ; idx += 512) {
    int p = idx >= FQ;
    int q = idx - p * FQ;
    int t0 = 2 * q + p - 48;
    float f0 = (t0 >= 0 && t0 < FS) ? filters[r * FS + t0] : 0.f;
    float f1 = (t0 + 1 >= 0 && t0 + 1 < FS) ? filters[r * FS + t0 + 1] : 0.f;
    union { _Float16 h[2]; unsigned u; } P;
    P.h[0] = (_Float16)f0;
    P.h[1] = (_Float16)f1;
    fcp[idx] = P.u;
  }

  // ---- energy staging: pairs, f16*1024, XOR-swizzled granule layout ----
  {
    unsigned* er32 = (unsigned*)er;
    for (int x2 = tid; x2 < ER_N / 2; x2 += 512) {
      int x = 2 * x2;
      union { _Float16 h[2]; unsigned u; } P;
#pragma unroll
      for (int k = 0; k < 2; ++k) {
        int n = E0 - x - k;
        float e = 0.f;
        if (n >= 0 && n < NS) {
          float pos = ((float)n + 0.5f) * (1.f / 256.f) - 0.5f;
          pos = fminf(fmaxf(pos, 0.f), 511.f);
          float fi = floorf(pos);
          int i0 = (int)fi;
          int i1 = min(i0 + 1, 511);
          float fr = pos - fi;
          float u = rp[i0] * (1.f - fr) + rp[i1] * fr;
          e = u * npz[n];
        }
        P.h[k] = (_Float16)(e * 1024.f);
      }
      int g = x >> 3;
      int sig = g ^ ((g >> 3) & 7);
      er32[sig * 4 + ((x & 7) >> 1)] = P.u;
    }
  }
  __syncthreads();

  const int w = tid >> 6;
  const int l = tid & 63;
  const int row = l & 31;   // A-row m == B-col n lane index
  const int h = l >> 5;     // k-half
  const int p = row & 1;

  // A granule per tile: g = 4096 - 512w - 128*tau + 4row + h + 2*sg
  int ga0 = 4096 - 512 * w + 4 * row + h;
  int ga1 = ga0 - 128;
  int ga2 = ga0 - 256;
  int ga3 = ga0 - 384;
  // B dword base (phase 0): q = (row-p)/2 + 8 + 4h + p*FQ, += 8 per sg
  int qB = ((row - p) >> 1) + 8 + 4 * h + p * FQ;

  f32x16 a00, a01, a02, a03, a10, a11, a12, a13;
#pragma unroll
  for (int i = 0; i < 16; ++i) {
    a00[i] = 0.f; a01[i] = 0.f; a02[i] = 0.f; a03[i] = 0.f;
    a10[i] = 0.f; a11[i] = 0.f; a12[i] = 0.f; a13[i] = 0.f;
  }

#define LOADB(DST, Q)                                                         \
  union { unsigned u[4]; f16x8 v; } DST;                                      \
  DST.u[0] = fcp[(Q)]; DST.u[1] = fcp[(Q) + 1];                               \
  DST.u[2] = fcp[(Q) + 2]; DST.u[3] = fcp[(Q) + 3];
#define LOADA(DST, G)                                                         \
  union { uint4 u; f16x8 v; } DST;                                            \
  { int ab = ((G) ^ (((G) >> 3) & 7)) << 4;                                   \
    DST.u = *(const uint4*)((const unsigned char*)er + ab); }

  // ---- prologue: 2 supersteps, phase 0 only ----
  for (int sg = 0; sg < 2; ++sg) {
    LOADB(Bf, qB)
    LOADA(A0, ga0) LOADA(A1, ga1) LOADA(A2, ga2) LOADA(A3, ga3)
    a00 = __builtin_amdgcn_mfma_f32_32x32x16_f16(A0.v, Bf.v, a00, 0, 0, 0);
    a01 = __builtin_amdgcn_mfma_f32_32x32x16_f16(A1.v, Bf.v, a01, 0, 0, 0);
    a02 = __builtin_amdgcn_mfma_f32_32x32x16_f16(A2.v, Bf.v, a02, 0, 0, 0);
    a03 = __builtin_amdgcn_mfma_f32_32x32x16_f16(A3.v, Bf.v, a03, 0, 0, 0);
    ga0 += 2; ga1 += 2; ga2 += 2; ga3 += 2; qB += 8;
  }
  // ---- main: 64 supersteps, both phases (A shared) ----
  for (int sg = 0; sg < 64; ++sg) {
    LOADB(B0, qB)
    LOADB(B1, qB + 512)
    LOADA(A0, ga0) LOADA(A1, ga1) LOADA(A2, ga2) LOADA(A3, ga3)
    a00 = __builtin_amdgcn_mfma_f32_32x32x16_f16(A0.v, B0.v, a00, 0, 0, 0);
    a10 = __builtin_amdgcn_mfma_f32_32x32x16_f16(A0.v, B1.v, a10, 0, 0, 0);
    a01 = __builtin_amdgcn_mfma_f32_32x32x16_f16(A1.v, B0.v, a01, 0, 0, 0);
    a11 = __builtin_amdgcn_mfma_f32_32x32x16_f16(A1.v, B1.v, a11, 0, 0, 0);
    a02 = __builtin_amdgcn_mfma_f32_32x32x16_f16(A2.v, B0.v, a02, 0, 0, 0);
    a12 = __builtin_amdgcn_mfma_f32_32x32x16_f16(A2.v, B1.v, a12, 0, 0, 0);
    a03 = __builtin_amdgcn_mfma_f32_32x32x16_f16(A3.v, B0.v, a03, 0, 0, 0);
    a13 = __builtin_amdgcn_mfma_f32_32x32x16_f16(A3.v, B1.v, a13, 0, 0, 0);
    ga0 += 2; ga1 += 2; ga2 += 2; ga3 += 2; qB += 8;
  }

  // ---- r6 FIX: global-top orphan strip gets its phase-0 half here ----
  if (seg == 3 && w == 7) {
    f32x16 ax;
#pragma unroll
    for (int i = 0; i < 16; ++i) ax[i] = 0.f;
    int ge = 4 * row + h;                              // (E0 - Q4)/8 = 0
    int qx = ((row - p) >> 1) + 8 + 4 * h + p * FQ;
    for (int sg = 0; sg < 66; ++sg) {
      LOADB(Bx, qx)
      LOADA(Ax, ge)
      ax = __builtin_amdgcn_mfma_f32_32x32x16_f16(Ax.v, Bx.v, ax, 0, 0, 0);
      ge += 2; qx += 8;
    }
#pragma unroll
    for (int i = 0; i < 16; ++i) a13[i] += ax[i];
  }
#undef LOADA
#undef LOADB

  // ---- epilogue ----
  // col = row (lane&31), crow = (rg&3)+8*(rg>>2)+4h; y = base + col - 32*crow
  float* cbase = outp + (size_t)chan * NS;
  const float scale = 1.f / 1024.f;

#define SUMSTORE(P0, P1, U)                                                   \
  {                                                                           \
    float* po = cbase + SegB + 4096 * w + 1024 * (U);                         \
    _Pragma("unroll")                                                         \
    for (int rg = 0; rg < 16; ++rg) {                                         \
      int crow = (rg & 3) + 8 * (rg >> 2) + 4 * h;                            \
      po[row - 32 * crow] = (P0[rg] + P1[rg]) * scale;                        \
    }                                                                         \
  }
  SUMSTORE(a01, a10, 1)
  SUMSTORE(a02, a11, 2)
  SUMSTORE(a03, a12, 3)
#undef SUMSTORE

  // exchange a13 (wave w) -> partner of wave w+1's a00
  __syncthreads();                       // everyone done reading er
  float* scr = (float*)smem;             // 8 waves x 16 regs x 64 lanes
#pragma unroll
  for (int rg = 0; rg < 16; ++rg) scr[w * 1024 + rg * 64 + l] = a13[rg];
  __syncthreads();

  if (w >= 1) {
    float* po = cbase + SegB + 4096 * w;
#pragma unroll
    for (int rg = 0; rg < 16; ++rg) {
      int crow = (rg & 3) + 8 * (rg >> 2) + 4 * h;
      po[row - 32 * crow] = (a00[rg] + scr[(w - 1) * 1024 + rg * 64 + l]) * scale;
    }
  } else {
    // w == 0: partial strip [SegB-992, SegB+32) -> atomicAdd (pre-zeroed)
#pragma unroll
    for (int rg = 0; rg < 16; ++rg) {
      int crow = (rg & 3) + 8 * (rg >> 2) + 4 * h;
      int y = SegB + row - 32 * crow;
      if (y >= 0) atomicAdd(cbase + y, a00[rg] * scale);
    }
  }
  if (w == 7) {
    // partial strip [SegB+31776, SegB+32800) -> atomicAdd (pre-zeroed)
#pragma unroll
    for (int rg = 0; rg < 16; ++rg) {
      int crow = (rg & 3) + 8 * (rg >> 2) + 4 * h;
      int y = SegB + 32768 + row - 32 * crow;
      if (y < NS) atomicAdd(cbase + y, a13[rg] * scale);
    }
  }
}

// ---------------------------------------------------------------------------
extern "C" void kernel_launch(void* const* d_in, const int* in_sizes, int n_in,
                              void* d_out, int out_size, void* d_ws, size_t ws_size,
                              hipStream_t stream) {
  const float* forces     = (const float*)d_in[0];
  const float* dmod       = (const float*)d_in[1];
  const float* noise      = (const float*)d_in[2];
  const float* dparam     = (const float*)d_in[3];
  const float* routing    = (const float*)d_in[4];
  const float* W1         = (const float*)d_in[5];
  const float* b1         = (const float*)d_in[6];
  const float* W2         = (const float*)d_in[7];
  const float* b2         = (const float*)d_in[8];
  const float* filters    = (const float*)d_in[9];
  const float* to_control = (const float*)d_in[10];

  float* out = (float*)d_out;
  float* to_ctrl = out;                                  // (B,CPD,NF)
  float* reso = out + BATCH * CPD * NF;                  // (B,RES,NS)

  float* damped_t = (float*)d_ws;                        // (B,NF,CPD)
  float* routed = damped_t + BATCH * NF * CPD;           // (B,RES,NF)

  k_scan<<<BATCH, 256, 0, stream>>>(forces, dmod, dparam, damped_t);
  k_hyper<<<BATCH * NF / 4, 256, 0, stream>>>(damped_t, routing, W1, b1, W2, b2,
                                              to_control, routed, to_ctrl);
  k_zero<<<BATCH * RES, 256, 0, stream>>>(reso);
  k_conv<<<BATCH * RES * (NS / 32768), 512, 0, stream>>>(routed, noise, filters, reso);
}